// Round 6
// baseline (195.232 us; speedup 1.0000x reference)
//
#include <hip/hip_runtime.h>

#define SQL  1024
#define EDIM 256
#define NHD  8
#define NKV  (NHD * 3 * EDIM)   // 6144
#define MROWS (4 * SQL)         // 4096

typedef short bf16x8 __attribute__((ext_vector_type(8)));
typedef float f32x4 __attribute__((ext_vector_type(4)));

__device__ __forceinline__ unsigned short f2bf(float f) {
  unsigned u = __float_as_uint(f);
  u += 0x7fff + ((u >> 16) & 1);   // round-to-nearest-even (finite values)
  return (unsigned short)(u >> 16);
}
__device__ __forceinline__ float bf2f(unsigned short s) {
  return __uint_as_float(((unsigned)s) << 16);
}

// async 16B global->LDS (LDS dest = wave-uniform base + lane*16)
__device__ __forceinline__ void g2lds16(const void* g, void* l) {
  __builtin_amdgcn_global_load_lds(
      (const __attribute__((address_space(1))) unsigned int*)g,
      (__attribute__((address_space(3))) unsigned int*)l, 16, 0, 0);
}

__device__ __forceinline__ void storev(float* p, float v) { *p = v; }
__device__ __forceinline__ void storev(unsigned short* p, float v) { *p = f2bf(v); }

// =====================================================================
// Fused fp32 -> bf16 casts for x, w_attn, w_out (one launch).
// Blocks [0,512): x | [512,1280): w_attn | [1280,1536): w_out.
// =====================================================================
__global__ __launch_bounds__(256) void cast3_bf16(
    const float* __restrict__ x, unsigned short* __restrict__ xb,
    const float* __restrict__ wa, unsigned short* __restrict__ wb,
    const float* __restrict__ wo, unsigned short* __restrict__ wob) {
  const float* src; unsigned short* dst; int i;
  int blk = blockIdx.x;
  if (blk < 512)       { src = x;  dst = xb;  i = blk * 256 + threadIdx.x; }
  else if (blk < 1280) { src = wa; dst = wb;  i = (blk - 512) * 256 + threadIdx.x; }
  else                 { src = wo; dst = wob; i = (blk - 1280) * 256 + threadIdx.x; }
  float4 a = ((const float4*)src)[2 * i];
  float4 b = ((const float4*)src)[2 * i + 1];
  union { unsigned short s[8]; ulonglong2 v; } u;
  u.s[0] = f2bf(a.x); u.s[1] = f2bf(a.y); u.s[2] = f2bf(a.z); u.s[3] = f2bf(a.w);
  u.s[4] = f2bf(b.x); u.s[5] = f2bf(b.y); u.s[6] = f2bf(b.z); u.s[7] = f2bf(b.w);
  ((ulonglong2*)dst)[i] = u.v;
}

// =====================================================================
// bf16 MFMA NT-GEMM, double-buffered global_load_lds staging.
// =====================================================================
template <int BM, int BN, typename OutT>
__global__ __launch_bounds__(256) void gemm_mfma(
    const unsigned short* __restrict__ A, const unsigned short* __restrict__ B,
    const float* __restrict__ bias, OutT* __restrict__ C,
    int M, int N, int K) {
  constexpr int TM = BM / 32, TN = BN / 32;
  __shared__ __align__(16) unsigned short As[2][BM * 32];
  __shared__ __align__(16) unsigned short Bs[2][BN * 32];
  const int tid = threadIdx.x;
  const int wave = tid >> 6, lane = tid & 63;
  const int quad = lane >> 4, l16 = lane & 15;
  const int wm = (wave >> 1) * (BM / 2), wn = (wave & 1) * (BN / 2);
  const int m0 = blockIdx.x * BM, n0 = blockIdx.y * BN;
  const int sw = (l16 >> 1) & 3;

  f32x4 acc[TM][TN];
  #pragma unroll
  for (int i = 0; i < TM; i++)
    #pragma unroll
    for (int j = 0; j < TN; j++) acc[i][j] = {0.f, 0.f, 0.f, 0.f};

  auto stage = [&](int k0, int bb) {
    #pragma unroll
    for (int it = 0; it < BM / 64; it++) {
      int flat = it * 256 + tid;
      int row = flat >> 2;
      int cg = (flat & 3) ^ ((row >> 1) & 3);
      g2lds16(A + (size_t)(m0 + row) * K + k0 + cg * 8, &As[bb][flat * 8]);
    }
    #pragma unroll
    for (int it = 0; it < BN / 64; it++) {
      int flat = it * 256 + tid;
      int row = flat >> 2;
      int cg = (flat & 3) ^ ((row >> 1) & 3);
      g2lds16(B + (size_t)(n0 + row) * K + k0 + cg * 8, &Bs[bb][flat * 8]);
    }
  };

  stage(0, 0);
  __syncthreads();
  for (int k0 = 0; k0 < K; k0 += 32) {
    const int bb = (k0 >> 5) & 1;
    if (k0 + 32 < K) stage(k0 + 32, bb ^ 1);
    bf16x8 af[TM], bf[TN];
    #pragma unroll
    for (int i = 0; i < TM; i++)
      af[i] = *(const bf16x8*)&As[bb][(wm + i * 16 + l16) * 32 + (quad ^ sw) * 8];
    #pragma unroll
    for (int j = 0; j < TN; j++)
      bf[j] = *(const bf16x8*)&Bs[bb][(wn + j * 16 + l16) * 32 + (quad ^ sw) * 8];
    #pragma unroll
    for (int i = 0; i < TM; i++)
      #pragma unroll
      for (int j = 0; j < TN; j++)
        acc[i][j] = __builtin_amdgcn_mfma_f32_16x16x32_bf16(af[i], bf[j], acc[i][j], 0, 0, 0);
    __syncthreads();
  }

  #pragma unroll
  for (int i = 0; i < TM; i++) {
    #pragma unroll
    for (int r = 0; r < 4; r++) {
      int m = m0 + wm + i * 16 + quad * 4 + r;
      #pragma unroll
      for (int j = 0; j < TN; j++) {
        int n = n0 + wn + j * 16 + l16;
        storev(&C[(size_t)m * N + n], acc[i][j][r] + bias[n]);
      }
    }
  }
}

// =====================================================================
// One-shot V transpose: raw-view V -> Vt[bh][d][s] bf16.
// =====================================================================
__global__ __launch_bounds__(256) void transpose_v(
    const unsigned short* __restrict__ proj, unsigned short* __restrict__ vt) {
  __shared__ unsigned short T[64][66];
  const int tid = threadIdx.x;
  const int s0 = blockIdx.x * 64, d0 = blockIdx.y * 64, bh = blockIdx.z;
  const int b = bh >> 3, h = bh & 7;
  #pragma unroll
  for (int it = 0; it < 2; it++) {
    int c = it * 256 + tid;
    int sr = c >> 3, k8 = (c & 7) * 8;
    int s = s0 + sr;
    const unsigned short* src = proj + (size_t)(b * SQL + h * 128 + (s >> 3)) * NKV
                                + 2 * 2048 + (s & 7) * 256 + d0 + k8;
    *(ulonglong2*)&T[sr][k8] = *(const ulonglong2*)src;
  }
  __syncthreads();
  #pragma unroll
  for (int it = 0; it < 2; it++) {
    int c = it * 256 + tid;
    int dr = c >> 3, s8 = (c & 7) * 8;
    unsigned short tmp[8];
    #pragma unroll
    for (int j = 0; j < 8; j++) tmp[j] = T[s8 + j][dr];
    unsigned short* dst = vt + ((size_t)bh * EDIM + d0 + dr) * SQL + s0 + s8;
    *(ulonglong2*)dst = *(ulonglong2*)tmp;
  }
}

// =====================================================================
// bf16 MFMA flash attention, round 6: causal split-K.
// TQ=128 (4 waves x 32-row strips), TK=32, dbuf'd staging, Q frags from
// global. Grid 512 = 32 bh x 8 qt x 2 K-halves; block (qt,ks) does
// 2(qt+1) iters; decode pairs g with g+256 so co-resident pairs sum to
// 18 iters (uniform). Each block emits locally-normalized O (bf16) + l
// (fp32); combine_split merges. Shift-free softmax (bounded scores).
// LDS 74 KB -> 2 blocks/CU; VGPR ~176 -> 8 waves/CU.
// =====================================================================
__global__ __launch_bounds__(256) void attn_mfma(
    const unsigned short* __restrict__ proj,
    const unsigned short* __restrict__ vt,
    unsigned short* __restrict__ opart,   // [2][32][1024][256] bf16
    float* __restrict__ lpart) {          // [2][32][1024] fp32
  // shorts: K0 @0 | K1 @8192 | V0 @16384 | V1 @24576 | Ps @32768 (4*32*40)
  __shared__ __align__(16) unsigned short lds[37888];

  const int tid = threadIdx.x;
  const int wave = tid >> 6, lane = tid & 63;
  const int quad = lane >> 4, l16 = lane & 15;
  // decode: bh = g&31; t = g>>5; t<8 -> (qt=7-t, ks=0) heavy-desc,
  // t>=8 -> (qt=t-8, ks=1) light-asc. Pair (g, g+256): 2(8-t)+2(t+1)=18.
  const int g = blockIdx.x;
  const int bh = g & 31;
  const int t = g >> 5;
  const int qt = (t < 8) ? (7 - t) : (t - 8);
  const int ks = (t < 8) ? 0 : 1;
  const int b = bh >> 3, h = bh & 7;
  const int q0 = qt * 128;
  const int nh = 2 * (qt + 1);      // iters for this block
  const int kt0 = ks * nh;          // first TK=32 tile index
  unsigned short* Ps = lds + 32768 + wave * 1280;  // [32][40]

  // ---- Q A-frags direct from global (coalesced 16B/lane) ----
  bf16x8 aq[2][8];
  #pragma unroll
  for (int st = 0; st < 2; st++) {
    int s = q0 + wave * 32 + st * 16 + l16;
    const unsigned short* qrow =
        proj + (size_t)(b * SQL + h * 128 + (s >> 3)) * NKV + (s & 7) * 256;
    #pragma unroll
    for (int kk = 0; kk < 8; kk++)
      aq[st][kk] = *(const bf16x8*)(qrow + kk * 32 + quad * 8);
  }

  auto stage = [&](int kt, int bb) {
    unsigned short* KsB = lds + bb * 8192;
    unsigned short* VtB = lds + 16384 + bb * 8192;
    #pragma unroll
    for (int it = 0; it < 4; it++) {   // K tile 32 x 256
      int flat = it * 256 + tid;
      int row = flat >> 5, ch = (flat & 31) ^ (row & 7);
      int s = kt * 32 + row;
      g2lds16(proj + (size_t)(b * SQL + h * 128 + (s >> 3)) * NKV + 2048
                   + (s & 7) * 256 + ch * 8,
              KsB + flat * 8);
    }
    #pragma unroll
    for (int it = 0; it < 4; it++) {   // Vt tile 256 x 32
      int flat = it * 256 + tid;
      int d = flat >> 2, ch = (flat & 3) ^ ((d >> 1) & 3);
      g2lds16(vt + ((size_t)bh * EDIM + d) * SQL + kt * 32 + ch * 8,
              VtB + flat * 8);
    }
  };

  f32x4 o[2][16];
  #pragma unroll
  for (int st = 0; st < 2; st++)
    #pragma unroll
    for (int tt = 0; tt < 16; tt++) o[st][tt] = {0.f, 0.f, 0.f, 0.f};
  float l_r[2][4] = {};

  stage(kt0, 0);
  __syncthreads();

  for (int i = 0; i < nh; i++) {
    const int kt = kt0 + i;
    const int bb = i & 1;
    if (i + 1 < nh) stage(kt + 1, bb ^ 1);  // prefetch, drained at barrier
    const unsigned short* KsB = lds + bb * 8192;
    const unsigned short* VtB = lds + 16384 + bb * 8192;

    // ---- S = Q K^T : 2 strips x 2 col-tiles, B-frags shared by strips ----
    f32x4 s[2][2];
    #pragma unroll
    for (int st = 0; st < 2; st++)
      #pragma unroll
      for (int c = 0; c < 2; c++) s[st][c] = {0.f, 0.f, 0.f, 0.f};
    #pragma unroll
    for (int c = 0; c < 2; c++) {
      #pragma unroll
      for (int kk = 0; kk < 8; kk++) {
        int ch = (kk * 4 + quad) ^ (l16 & 7);
        bf16x8 bk = *(const bf16x8*)&KsB[(c * 16 + l16) * 256 + ch * 8];
        s[0][c] = __builtin_amdgcn_mfma_f32_16x16x32_bf16(aq[0][kk], bk, s[0][c], 0, 0, 0);
        s[1][c] = __builtin_amdgcn_mfma_f32_16x16x32_bf16(aq[1][kk], bk, s[1][c], 0, 0, 0);
      }
    }

    // ---- shift-free softmax -> Ps (bf16), lane-local l partials ----
    #pragma unroll
    for (int st = 0; st < 2; st++) {
      #pragma unroll
      for (int c = 0; c < 2; c++) {
        int kg = kt * 32 + c * 16 + l16;
        #pragma unroll
        for (int r = 0; r < 4; r++) {
          int qg = q0 + wave * 32 + st * 16 + quad * 4 + r;
          float p = (kg <= qg) ? __expf(s[st][c][r] * 0.0625f) : 0.f;
          l_r[st][r] += p;
          Ps[(st * 16 + quad * 4 + r) * 40 + c * 16 + l16] = f2bf(p);
        }
      }
    }

    // ---- PV: P (C->A via per-wave LDS, no barrier), Vt B-frags shared ----
    bf16x8 ap0 = *(const bf16x8*)&Ps[l16 * 40 + quad * 8];
    bf16x8 ap1 = *(const bf16x8*)&Ps[(16 + l16) * 40 + quad * 8];
    #pragma unroll
    for (int tt = 0; tt < 16; tt++) {
      int ch = quad ^ ((l16 >> 1) & 3);
      bf16x8 bv = *(const bf16x8*)&VtB[(tt * 16 + l16) * 32 + ch * 8];
      o[0][tt] = __builtin_amdgcn_mfma_f32_16x16x32_bf16(ap0, bv, o[0][tt], 0, 0, 0);
      o[1][tt] = __builtin_amdgcn_mfma_f32_16x16x32_bf16(ap1, bv, o[1][tt], 0, 0, 0);
    }
    __syncthreads();  // buffer swap gate + drains prefetch
  }

  // ---- epilogue: reduce l, write locally-normalized O (bf16) + l ----
  #pragma unroll
  for (int st = 0; st < 2; st++) {
    #pragma unroll
    for (int r = 0; r < 4; r++) {
      float l = l_r[st][r];
      #pragma unroll
      for (int off = 1; off < 16; off <<= 1) l += __shfl_xor(l, off);
      float inv = (l > 0.f) ? 1.0f / l : 0.f;
      int s = q0 + wave * 32 + st * 16 + quad * 4 + r;
      size_t rowidx = (size_t)ks * 32768 + bh * 1024 + s;
      if (l16 == 0) lpart[rowidx] = l;
      unsigned short* dst = opart + rowidx * 256;
      #pragma unroll
      for (int tt = 0; tt < 16; tt++)
        dst[tt * 16 + l16] = f2bf(o[st][tt][r] * inv);
    }
  }
}

// =====================================================================
// Merge split-K partials: obf = (O1*l1 + O2*l2)/(l1+l2), raw-view layout.
// =====================================================================
__global__ __launch_bounds__(256) void combine_split(
    const unsigned short* __restrict__ opart, const float* __restrict__ lpart,
    unsigned short* __restrict__ obf) {
  int idx = blockIdx.x * 256 + threadIdx.x;   // [0, 32768*32)
  int row = idx >> 5;                         // (bh,s) row in [0,32768)
  int oct = idx & 31;                         // 8-elem group in d
  int bh = row >> 10, s = row & 1023;
  float l1 = lpart[row], l2 = lpart[32768 + row];
  float w = 1.0f / (l1 + l2);
  union { unsigned short s[8]; ulonglong2 v; } u1, u2, uo;
  u1.v = *(const ulonglong2*)(opart + (size_t)row * 256 + oct * 8);
  u2.v = *(const ulonglong2*)(opart + (size_t)(32768 + row) * 256 + oct * 8);
  #pragma unroll
  for (int j = 0; j < 8; j++)
    uo.s[j] = f2bf((bf2f(u1.s[j]) * l1 + bf2f(u2.s[j]) * l2) * w);
  int b = bh >> 3, h = bh & 7;
  unsigned short* dst = obf + (size_t)(b * SQL + h * 128 + (s >> 3)) * 2048
                        + (s & 7) * 256 + oct * 8;
  *(ulonglong2*)dst = uo.v;
}

extern "C" void kernel_launch(void* const* d_in, const int* in_sizes, int n_in,
                              void* d_out, int out_size, void* d_ws, size_t ws_size,
                              hipStream_t stream) {
  const float* x      = (const float*)d_in[0];
  const float* w_attn = (const float*)d_in[1];
  const float* b_attn = (const float*)d_in[2];
  const float* w_out  = (const float*)d_in[3];
  const float* b_out  = (const float*)d_in[4];
  float* out = (float*)d_out;

  // ws: proj 50.3 | obf 16.8 | vtb 16.8 | xb 2 | wb 3.1 | wob 1 |
  //     opart 33.6 | lpart 0.26  (~124 MB)
  char* p = (char*)d_ws;
  unsigned short* proj  = (unsigned short*)p;  p += (size_t)MROWS * NKV * 2;
  unsigned short* obf   = (unsigned short*)p;  p += (size_t)MROWS * 2048 * 2;
  unsigned short* vtb   = (unsigned short*)p;  p += (size_t)32 * EDIM * SQL * 2;
  unsigned short* xb    = (unsigned short*)p;  p += (size_t)MROWS * EDIM * 2;
  unsigned short* wb    = (unsigned short*)p;  p += (size_t)NKV * EDIM * 2;
  unsigned short* wob   = (unsigned short*)p;  p += (size_t)EDIM * 2048 * 2;
  unsigned short* opart = (unsigned short*)p;  p += (size_t)2 * 32768 * 256 * 2;
  float*          lpart = (float*)p;

  cast3_bf16<<<1536, 256, 0, stream>>>(x, xb, w_attn, wb, w_out, wob);
  gemm_mfma<128, 128, unsigned short><<<dim3(MROWS / 128, NKV / 128), 256, 0, stream>>>(
      xb, wb, b_attn, proj, MROWS, NKV, EDIM);
  transpose_v<<<dim3(SQL / 64, EDIM / 64, 32), 256, 0, stream>>>(proj, vtb);
  attn_mfma<<<512, 256, 0, stream>>>(proj, vtb, opart, lpart);
  combine_split<<<4096, 256, 0, stream>>>(opart, lpart, obf);
  gemm_mfma<64, 64, float><<<dim3(MROWS / 64, EDIM / 64), 256, 0, stream>>>(
      obf, wob, b_out, out, MROWS, EDIM, NHD * EDIM);
}

// Round 8
// 189.098 us; speedup vs baseline: 1.0324x; 1.0324x over previous
//
#include <hip/hip_runtime.h>

#define SQL  1024
#define EDIM 256
#define NHD  8
#define NKV  (NHD * 3 * EDIM)   // 6144
#define MROWS (4 * SQL)         // 4096

typedef short bf16x8 __attribute__((ext_vector_type(8)));
typedef float f32x4 __attribute__((ext_vector_type(4)));

__device__ __forceinline__ unsigned short f2bf(float f) {
  unsigned u = __float_as_uint(f);
  u += 0x7fff + ((u >> 16) & 1);   // round-to-nearest-even (finite values)
  return (unsigned short)(u >> 16);
}
__device__ __forceinline__ float bf2f(unsigned short s) {
  return __uint_as_float(((unsigned)s) << 16);
}

// async 16B global->LDS (LDS dest = wave-uniform base + lane*16)
__device__ __forceinline__ void g2lds16(const void* g, void* l) {
  __builtin_amdgcn_global_load_lds(
      (const __attribute__((address_space(1))) unsigned int*)g,
      (__attribute__((address_space(3))) unsigned int*)l, 16, 0, 0);
}

__device__ __forceinline__ void storev(float* p, float v) { *p = v; }
__device__ __forceinline__ void storev(unsigned short* p, float v) { *p = f2bf(v); }

// =====================================================================
// Fused fp32 -> bf16 casts for x, w_attn, w_out (one launch).
// =====================================================================
__global__ __launch_bounds__(256) void cast3_bf16(
    const float* __restrict__ x, unsigned short* __restrict__ xb,
    const float* __restrict__ wa, unsigned short* __restrict__ wb,
    const float* __restrict__ wo, unsigned short* __restrict__ wob) {
  const float* src; unsigned short* dst; int i;
  int blk = blockIdx.x;
  if (blk < 512)       { src = x;  dst = xb;  i = blk * 256 + threadIdx.x; }
  else if (blk < 1280) { src = wa; dst = wb;  i = (blk - 512) * 256 + threadIdx.x; }
  else                 { src = wo; dst = wob; i = (blk - 1280) * 256 + threadIdx.x; }
  float4 a = ((const float4*)src)[2 * i];
  float4 b = ((const float4*)src)[2 * i + 1];
  union { unsigned short s[8]; ulonglong2 v; } u;
  u.s[0] = f2bf(a.x); u.s[1] = f2bf(a.y); u.s[2] = f2bf(a.z); u.s[3] = f2bf(a.w);
  u.s[4] = f2bf(b.x); u.s[5] = f2bf(b.y); u.s[6] = f2bf(b.z); u.s[7] = f2bf(b.w);
  ((ulonglong2*)dst)[i] = u.v;
}

// =====================================================================
// bf16 MFMA NT-GEMM, double-buffered global_load_lds staging.
// =====================================================================
template <int BM, int BN, typename OutT>
__global__ __launch_bounds__(256) void gemm_mfma(
    const unsigned short* __restrict__ A, const unsigned short* __restrict__ B,
    const float* __restrict__ bias, OutT* __restrict__ C,
    int M, int N, int K) {
  constexpr int TM = BM / 32, TN = BN / 32;
  __shared__ __align__(16) unsigned short As[2][BM * 32];
  __shared__ __align__(16) unsigned short Bs[2][BN * 32];
  const int tid = threadIdx.x;
  const int wave = tid >> 6, lane = tid & 63;
  const int quad = lane >> 4, l16 = lane & 15;
  const int wm = (wave >> 1) * (BM / 2), wn = (wave & 1) * (BN / 2);
  const int m0 = blockIdx.x * BM, n0 = blockIdx.y * BN;
  const int sw = (l16 >> 1) & 3;

  f32x4 acc[TM][TN];
  #pragma unroll
  for (int i = 0; i < TM; i++)
    #pragma unroll
    for (int j = 0; j < TN; j++) acc[i][j] = {0.f, 0.f, 0.f, 0.f};

  auto stage = [&](int k0, int bb) {
    #pragma unroll
    for (int it = 0; it < BM / 64; it++) {
      int flat = it * 256 + tid;
      int row = flat >> 2;
      int cg = (flat & 3) ^ ((row >> 1) & 3);
      g2lds16(A + (size_t)(m0 + row) * K + k0 + cg * 8, &As[bb][flat * 8]);
    }
    #pragma unroll
    for (int it = 0; it < BN / 64; it++) {
      int flat = it * 256 + tid;
      int row = flat >> 2;
      int cg = (flat & 3) ^ ((row >> 1) & 3);
      g2lds16(B + (size_t)(n0 + row) * K + k0 + cg * 8, &Bs[bb][flat * 8]);
    }
  };

  stage(0, 0);
  __syncthreads();
  for (int k0 = 0; k0 < K; k0 += 32) {
    const int bb = (k0 >> 5) & 1;
    if (k0 + 32 < K) stage(k0 + 32, bb ^ 1);
    bf16x8 af[TM], bf[TN];
    #pragma unroll
    for (int i = 0; i < TM; i++)
      af[i] = *(const bf16x8*)&As[bb][(wm + i * 16 + l16) * 32 + (quad ^ sw) * 8];
    #pragma unroll
    for (int j = 0; j < TN; j++)
      bf[j] = *(const bf16x8*)&Bs[bb][(wn + j * 16 + l16) * 32 + (quad ^ sw) * 8];
    #pragma unroll
    for (int i = 0; i < TM; i++)
      #pragma unroll
      for (int j = 0; j < TN; j++)
        acc[i][j] = __builtin_amdgcn_mfma_f32_16x16x32_bf16(af[i], bf[j], acc[i][j], 0, 0, 0);
    __syncthreads();
  }

  #pragma unroll
  for (int i = 0; i < TM; i++) {
    #pragma unroll
    for (int r = 0; r < 4; r++) {
      int m = m0 + wm + i * 16 + quad * 4 + r;
      #pragma unroll
      for (int j = 0; j < TN; j++) {
        int n = n0 + wn + j * 16 + l16;
        storev(&C[(size_t)m * N + n], acc[i][j][r] + bias[n]);
      }
    }
  }
}

// =====================================================================
// One-shot V transpose: raw-view V -> Vt[bh][d][s] bf16.
// =====================================================================
__global__ __launch_bounds__(256) void transpose_v(
    const unsigned short* __restrict__ proj, unsigned short* __restrict__ vt) {
  __shared__ unsigned short T[64][66];
  const int tid = threadIdx.x;
  const int s0 = blockIdx.x * 64, d0 = blockIdx.y * 64, bh = blockIdx.z;
  const int b = bh >> 3, h = bh & 7;
  #pragma unroll
  for (int it = 0; it < 2; it++) {
    int c = it * 256 + tid;
    int sr = c >> 3, k8 = (c & 7) * 8;
    int s = s0 + sr;
    const unsigned short* src = proj + (size_t)(b * SQL + h * 128 + (s >> 3)) * NKV
                                + 2 * 2048 + (s & 7) * 256 + d0 + k8;
    *(ulonglong2*)&T[sr][k8] = *(const ulonglong2*)src;
  }
  __syncthreads();
  #pragma unroll
  for (int it = 0; it < 2; it++) {
    int c = it * 256 + tid;
    int dr = c >> 3, s8 = (c & 7) * 8;
    unsigned short tmp[8];
    #pragma unroll
    for (int j = 0; j < 8; j++) tmp[j] = T[s8 + j][dr];
    unsigned short* dst = vt + ((size_t)bh * EDIM + d0 + dr) * SQL + s0 + s8;
    *(ulonglong2*)dst = *(ulonglong2*)tmp;
  }
}

// =====================================================================
// bf16 MFMA flash attention, round 8: static uniform split, no queue.
// Pair q-tile (7-j) [4(8-j) tiles] with q-tile j [4(j+1) tiles] -> 36
// tiles/pair; split the concatenated key sequence into 4 subs of 9.
// Grid 512 = 32 bh x 4 pairs x 4 subs: all blocks do exactly 9 TK=32
// iterations -> 18 iters/CU at 2 blocks/CU, mapping-independent.
// The one straddling sub per pair runs as 2 segments (own Q frags,
// own partial slot). 5 slots/pair; combine merges (linear partials).
// Inner loop identical to round 6 (verified swizzles, dbuf staging).
// =====================================================================
__global__ __launch_bounds__(256) void attn_mfma(
    const unsigned short* __restrict__ proj,
    const unsigned short* __restrict__ vt,
    unsigned short* __restrict__ opart,   // [640][128][256] bf16
    float* __restrict__ lpart) {          // [640][128] fp32
  // shorts: K0 @0 | K1 @8192 | V0 @16384 | V1 @24576 | Ps @32768 (4*32*40)
  __shared__ __align__(16) unsigned short lds[37888];

  const int tid = threadIdx.x;
  const int wave = tid >> 6, lane = tid & 63;
  const int quad = lane >> 4, l16 = lane & 15;
  unsigned short* Ps = lds + 32768 + wave * 1280;  // [32][40]

  const int g = blockIdx.x;
  const int bh = g & 31;
  const int rem = g >> 5;
  const int j = rem & 3;          // pair id
  const int sb = rem >> 2;        // sub id 0..3
  const int b = bh >> 3, h = bh & 7;
  const int t0 = 4 * (8 - j);     // member0 tile count (32,28,24,20)
  const int m0cnt = (j < 2) ? 4 : 3;   // ceil(t0/9)
  const int s1st  = (j < 2) ? 3 : 2;   // floor(t0/9)
  const int lo = 9 * sb, hi = lo + 9;

  // build up to 2 segments: {qt, local kt start, len, partial slot r}
  int segqt[2], segk0[2], seglen[2], segr[2];
  int nseg = 0;
  if (lo < t0) {  // member0 = q-tile 7-j
    int e = (hi < t0) ? hi : t0;
    segqt[nseg] = 7 - j; segk0[nseg] = lo; seglen[nseg] = e - lo;
    segr[nseg] = sb; nseg++;
  }
  if (hi > t0) {  // member1 = q-tile j
    int a = (lo > t0) ? lo : t0;
    segqt[nseg] = j; segk0[nseg] = a - t0; seglen[nseg] = hi - a;
    segr[nseg] = m0cnt + (sb - s1st); nseg++;
  }

  auto stage = [&](int kt, int bb) {
    unsigned short* KsB = lds + bb * 8192;
    unsigned short* VtB = lds + 16384 + bb * 8192;
    #pragma unroll
    for (int it = 0; it < 4; it++) {   // K tile 32 x 256
      int flat = it * 256 + tid;
      int row = flat >> 5, ch = (flat & 31) ^ (row & 7);
      int s = kt * 32 + row;
      g2lds16(proj + (size_t)(b * SQL + h * 128 + (s >> 3)) * NKV + 2048
                   + (s & 7) * 256 + ch * 8,
              KsB + flat * 8);
    }
    #pragma unroll
    for (int it = 0; it < 4; it++) {   // Vt tile 256 x 32
      int flat = it * 256 + tid;
      int d = flat >> 2, ch = (flat & 3) ^ ((d >> 1) & 3);
      g2lds16(vt + ((size_t)bh * EDIM + d) * SQL + kt * 32 + ch * 8,
              VtB + flat * 8);
    }
  };

  for (int sg = 0; sg < nseg; sg++) {
    const int qt = segqt[sg];
    const int q0 = qt * 128;
    const int c0 = segk0[sg], len = seglen[sg];

    // ---- Q A-frags direct from global (coalesced 16B/lane, L2-hot) ----
    bf16x8 aq[2][8];
    #pragma unroll
    for (int st = 0; st < 2; st++) {
      int s = q0 + wave * 32 + st * 16 + l16;
      const unsigned short* qrow =
          proj + (size_t)(b * SQL + h * 128 + (s >> 3)) * NKV + (s & 7) * 256;
      #pragma unroll
      for (int kk = 0; kk < 8; kk++)
        aq[st][kk] = *(const bf16x8*)(qrow + kk * 32 + quad * 8);
    }

    f32x4 o[2][16];
    #pragma unroll
    for (int st = 0; st < 2; st++)
      #pragma unroll
      for (int tt = 0; tt < 16; tt++) o[st][tt] = {0.f, 0.f, 0.f, 0.f};
    float l_r[2][4] = {};

    stage(c0, 0);
    __syncthreads();

    for (int i = 0; i < len; i++) {
      const int kt = c0 + i;
      const int bb = i & 1;
      if (i + 1 < len) stage(kt + 1, bb ^ 1);
      const unsigned short* KsB = lds + bb * 8192;
      const unsigned short* VtB = lds + 16384 + bb * 8192;

      // ---- S = Q K^T : 2 strips x 2 col-tiles, B-frags shared ----
      f32x4 s[2][2];
      #pragma unroll
      for (int st = 0; st < 2; st++)
        #pragma unroll
        for (int c = 0; c < 2; c++) s[st][c] = {0.f, 0.f, 0.f, 0.f};
      #pragma unroll
      for (int c = 0; c < 2; c++) {
        #pragma unroll
        for (int kk = 0; kk < 8; kk++) {
          int ch = (kk * 4 + quad) ^ (l16 & 7);
          bf16x8 bk = *(const bf16x8*)&KsB[(c * 16 + l16) * 256 + ch * 8];
          s[0][c] = __builtin_amdgcn_mfma_f32_16x16x32_bf16(aq[0][kk], bk, s[0][c], 0, 0, 0);
          s[1][c] = __builtin_amdgcn_mfma_f32_16x16x32_bf16(aq[1][kk], bk, s[1][c], 0, 0, 0);
        }
      }

      // ---- shift-free softmax -> Ps (bf16), lane-local l partials ----
      #pragma unroll
      for (int st = 0; st < 2; st++) {
        #pragma unroll
        for (int c = 0; c < 2; c++) {
          int kg = kt * 32 + c * 16 + l16;
          #pragma unroll
          for (int r = 0; r < 4; r++) {
            int qg = q0 + wave * 32 + st * 16 + quad * 4 + r;
            float p = (kg <= qg) ? __expf(s[st][c][r] * 0.0625f) : 0.f;
            l_r[st][r] += p;
            Ps[(st * 16 + quad * 4 + r) * 40 + c * 16 + l16] = f2bf(p);
          }
        }
      }

      // ---- PV: P C->A via per-wave LDS (no barrier), Vt B-frags shared ----
      bf16x8 ap0 = *(const bf16x8*)&Ps[l16 * 40 + quad * 8];
      bf16x8 ap1 = *(const bf16x8*)&Ps[(16 + l16) * 40 + quad * 8];
      #pragma unroll
      for (int tt = 0; tt < 16; tt++) {
        int ch = quad ^ ((l16 >> 1) & 3);
        bf16x8 bv = *(const bf16x8*)&VtB[(tt * 16 + l16) * 32 + ch * 8];
        o[0][tt] = __builtin_amdgcn_mfma_f32_16x16x32_bf16(ap0, bv, o[0][tt], 0, 0, 0);
        o[1][tt] = __builtin_amdgcn_mfma_f32_16x16x32_bf16(ap1, bv, o[1][tt], 0, 0, 0);
      }
      __syncthreads();  // buffer swap gate + drains prefetch
    }

    // ---- segment epilogue: reduce l, write normalized partial + l ----
    const int slot = (bh * 4 + j) * 5 + segr[sg];
    #pragma unroll
    for (int st = 0; st < 2; st++) {
      #pragma unroll
      for (int r = 0; r < 4; r++) {
        float l = l_r[st][r];
        #pragma unroll
        for (int off = 1; off < 16; off <<= 1) l += __shfl_xor(l, off);
        float inv = (l > 0.f) ? 1.0f / l : 0.f;
        int sl = wave * 32 + st * 16 + quad * 4 + r;   // local q-row [0,128)
        if (l16 == 0) lpart[slot * 128 + sl] = l;
        unsigned short* dst = opart + (size_t)slot * 32768 + sl * 256;
        #pragma unroll
        for (int tt = 0; tt < 16; tt++)
          dst[tt * 16 + l16] = f2bf(o[st][tt][r] * inv);
      }
    }
  }
}

// =====================================================================
// Merge partials per (bh,qt): obf = sum(O_r * l_r) / sum(l_r),
// written in raw-view layout. Exact (shift-free partials are linear).
// =====================================================================
__global__ __launch_bounds__(256) void combine_split(
    const unsigned short* __restrict__ opart, const float* __restrict__ lpart,
    unsigned short* __restrict__ obf) {
  int idx = blockIdx.x * 256 + threadIdx.x;   // [0, 32*1024*32)
  int row = idx >> 5, oct = idx & 31;
  int bh = row >> 10, s = row & 1023;
  int qt = s >> 7, sl = s & 127;
  int j, r0, rn;
  if (qt >= 4) {        // member0 of pair j = 7-qt
    j = 7 - qt; r0 = 0; rn = (j < 2) ? 4 : 3;
  } else {              // member1 of pair j = qt
    j = qt; int m0 = (j < 2) ? 4 : 3; r0 = m0; rn = 5 - m0;
  }
  int base = (bh * 4 + j) * 5;
  float acc[8] = {};
  float L = 0.f;
  for (int r = r0; r < r0 + rn; r++) {
    int slot = base + r;
    float l = lpart[slot * 128 + sl];
    L += l;
    union { unsigned short s[8]; ulonglong2 v; } u;
    u.v = *(const ulonglong2*)(opart + (size_t)slot * 32768 + sl * 256 + oct * 8);
    #pragma unroll
    for (int k = 0; k < 8; k++) acc[k] += bf2f(u.s[k]) * l;
  }
  float w = 1.0f / L;
  union { unsigned short s[8]; ulonglong2 v; } uo;
  #pragma unroll
  for (int k = 0; k < 8; k++) uo.s[k] = f2bf(acc[k] * w);
  int b = bh >> 3, h = bh & 7;
  unsigned short* dst = obf + (size_t)(b * SQL + h * 128 + (s >> 3)) * 2048
                        + (s & 7) * 256 + oct * 8;
  *(ulonglong2*)dst = uo.v;
}

extern "C" void kernel_launch(void* const* d_in, const int* in_sizes, int n_in,
                              void* d_out, int out_size, void* d_ws, size_t ws_size,
                              hipStream_t stream) {
  const float* x      = (const float*)d_in[0];
  const float* w_attn = (const float*)d_in[1];
  const float* b_attn = (const float*)d_in[2];
  const float* w_out  = (const float*)d_in[3];
  const float* b_out  = (const float*)d_in[4];
  float* out = (float*)d_out;

  // ws: proj 50.3 | vtb 16.8 (reused as obf after attn) | xb 2 | wb 3.1 |
  //     wob 1 | opart 41.9 | lpart 0.33  (~115.7 MB)
  char* p = (char*)d_ws;
  unsigned short* proj  = (unsigned short*)p;  p += (size_t)MROWS * NKV * 2;
  unsigned short* vtb   = (unsigned short*)p;  p += (size_t)32 * EDIM * SQL * 2;
  unsigned short* xb    = (unsigned short*)p;  p += (size_t)MROWS * EDIM * 2;
  unsigned short* wb    = (unsigned short*)p;  p += (size_t)NKV * EDIM * 2;
  unsigned short* wob   = (unsigned short*)p;  p += (size_t)EDIM * 2048 * 2;
  unsigned short* opart = (unsigned short*)p;  p += (size_t)640 * 32768 * 2;
  float*          lpart = (float*)p;
  unsigned short* obf   = vtb;   // vtb is dead after attn_mfma completes

  cast3_bf16<<<1536, 256, 0, stream>>>(x, xb, w_attn, wb, w_out, wob);
  gemm_mfma<128, 128, unsigned short><<<dim3(MROWS / 128, NKV / 128), 256, 0, stream>>>(
      xb, wb, b_attn, proj, MROWS, NKV, EDIM);
  transpose_v<<<dim3(SQL / 64, EDIM / 64, 32), 256, 0, stream>>>(proj, vtb);
  attn_mfma<<<512, 256, 0, stream>>>(proj, vtb, opart, lpart);
  combine_split<<<4096, 256, 0, stream>>>(opart, lpart, obf);
  gemm_mfma<64, 64, float><<<dim3(MROWS / 64, EDIM / 64), 256, 0, stream>>>(
      obf, wob, b_out, out, MROWS, EDIM, NHD * EDIM);
}